// Round 6
// baseline (177.890 us; speedup 1.0000x reference)
//
#include <hip/hip_runtime.h>
#include <hip/hip_cooperative_groups.h>
#include <math.h>

namespace cg = cooperative_groups;

#define N 8192
#define D 128
#define MARGIN 0.2f
#define PD_EPS 1e-6f
#define CLS_STRIDE 1024   // max rows per class bucket (16 classes, avg 512)
#define SUB_STRIDE 512    // max rows per subject bucket (32 subjects, avg 256)

typedef __attribute__((ext_vector_type(8))) short bf16x8;  // 8 bf16 = 4 VGPRs
typedef __attribute__((ext_vector_type(4))) float f32x4;

__device__ __forceinline__ unsigned short f2bf(float f) {
    unsigned u = __float_as_uint(f);
    u += 0x7FFFu + ((u >> 16) & 1u);   // round-to-nearest-even
    return (unsigned short)(u >> 16);
}
__device__ __forceinline__ unsigned umn(unsigned a, unsigned b) { return a < b ? a : b; }
__device__ __forceinline__ unsigned umx(unsigned a, unsigned b) { return a > b ? a : b; }

// One cooperative launch, 256 blocks x 256 threads (1 block/CU guaranteed
// co-resident). Phase A: blocks 0..47 build buckets (ballot compaction,
// labels/subjects preloaded to VGPRs), blocks 48..255 normalize rows.
// grid.sync. Phase B: 512 mining waves. grid.sync. Phase C: hinge + reduce.
__global__ __launch_bounds__(256, 1) void k_fused(const float* __restrict__ z,
                                                  const int* __restrict__ labels,
                                                  const int* __restrict__ subjects,
                                                  unsigned short* __restrict__ znb,
                                                  float* __restrict__ invn,
                                                  int* __restrict__ counters,
                                                  int* __restrict__ clsIdx,
                                                  int* __restrict__ subIdx,
                                                  unsigned* __restrict__ posk,
                                                  unsigned* __restrict__ negk,
                                                  float* __restrict__ acc,
                                                  float* __restrict__ out) {
    cg::grid_group grid = cg::this_grid();
    const int b = blockIdx.x;
    const int t = threadIdx.x;
    const int wave = t >> 6, lane = t & 63;

    __shared__ int wcnt[4];
    __shared__ int blkbase;
    __shared__ float ls[16], vs[16];

    // ---------------- phase A ----------------
    if (b < 48) {
        const bool isCls = b < 16;
        const int  tgt   = isCls ? b : b - 16;
        // preload the whole label/subject stream into registers
        int keyv[32], otherv[32];
        #pragma unroll
        for (int r = 0; r < 32; ++r) {
            int row = r * 256 + t;
            int lab = labels[row], sub = subjects[row];
            keyv[r]   = isCls ? lab : sub;
            otherv[r] = isCls ? sub : lab;
        }
        if (b == 0 && t < 3) acc[t] = 0.0f;   // loss-sum, valid-cnt, done-counter
        if (t == 0) blkbase = 0;
        __syncthreads();
        int* dst = isCls ? (clsIdx + tgt * CLS_STRIDE) : (subIdx + tgt * SUB_STRIDE);
        const int stride = isCls ? CLS_STRIDE : SUB_STRIDE;
        #pragma unroll
        for (int r = 0; r < 32; ++r) {
            bool pred = (keyv[r] == tgt);
            unsigned long long mask = __ballot(pred);
            int lrank = __popcll(mask & ((1ull << lane) - 1ull));
            if (lane == 0) wcnt[wave] = __popcll(mask);
            __syncthreads();
            int wb = 0;
            #pragma unroll
            for (int w = 0; w < 4; ++w) if (w < wave) wb += wcnt[w];
            int tot = wcnt[0] + wcnt[1] + wcnt[2] + wcnt[3];
            int pos = blkbase + wb + lrank;
            if (pred && pos < stride) dst[pos] = (otherv[r] << 13) | (r * 256 + t);
            __syncthreads();
            if (t == 0) blkbase += tot;
        }
        __syncthreads();
        if (t == 0) counters[isCls ? tgt : 16 + tgt] = blkbase;
    } else {
        // normalize: 40 rows per block (10 passes x 4 rows)
        for (int p = 0; p < 10; ++p) {
            int row = (b - 48) * 40 + p * 4 + wave;
            if (row < N) {
                float2 v = ((const float2*)(z + (size_t)row * D))[lane];
                float ss = v.x * v.x + v.y * v.y;
                #pragma unroll
                for (int m = 1; m < 64; m <<= 1) ss += __shfl_xor(ss, m, 64);
                float norm = fmaxf(sqrtf(ss), 1e-12f);
                ushort2 bb; bb.x = f2bf(v.x / norm); bb.y = f2bf(v.y / norm);
                ((ushort2*)(znb + (size_t)row * D))[lane] = bb;
                if (lane == 0) invn[row] = 1.0f / norm;
            }
        }
    }

    grid.sync();

    // ---------------- phase B: mining (512 units over 1024 waves) ------------
    {
        const int gw = b * 4 + wave;
        bool active = gw < 512;
        const int* idx = nullptr; int cnt = 0, atile = 0; bool isPos = false;
        if (active) {
            isPos = gw < 256;
            if (isPos) {
                int c = gw >> 4; atile = gw & 15;
                idx = clsIdx + c * CLS_STRIDE;
                cnt = min(counters[c], CLS_STRIDE);
            } else {
                int tt = gw - 256; int su = tt >> 3; atile = tt & 7;
                idx = subIdx + su * SUB_STRIDE;
                cnt = min(counters[16 + su], SUB_STRIDE);
            }
            if (atile * 64 >= cnt) active = false;
        }
        if (active) {
            const int m = lane & 15, quad = lane >> 4;

            // A fragments (A[m=lane&15][k=quad*8+j], m89-verified)
            bf16x8 afrag[4][4];
            #pragma unroll
            for (int u = 0; u < 4; ++u) {
                int sl = min(atile * 64 + u * 16 + m, cnt - 1);
                size_t row = (size_t)(idx[sl] & 8191);
                #pragma unroll
                for (int s = 0; s < 4; ++s)
                    afrag[u][s] = *(const bf16x8*)(znb + row * D + s * 32 + quad * 8);
            }
            int cpk[16];
            #pragma unroll
            for (int u = 0; u < 4; ++u)
                #pragma unroll
                for (int r = 0; r < 4; ++r)
                    cpk[u * 4 + r] = idx[min(atile * 64 + u * 16 + quad * 4 + r, cnt - 1)];

            unsigned best[16];
            #pragma unroll
            for (int s = 0; s < 16; ++s) best[s] = isPos ? 0xFFFFFFFFu : 0u;

            const int njt = (cnt + 63) >> 6;
            for (int tt = 0; tt < njt; ++tt) {
                int pkB[4];
                #pragma unroll
                for (int v = 0; v < 4; ++v)
                    pkB[v] = idx[min(tt * 64 + v * 16 + m, cnt - 1)];

                f32x4 ac[4][4];
                #pragma unroll
                for (int u = 0; u < 4; ++u)
                    #pragma unroll
                    for (int v = 0; v < 4; ++v)
                        ac[u][v] = (f32x4){0.f, 0.f, 0.f, 0.f};

                #pragma unroll
                for (int s = 0; s < 4; ++s) {
                    bf16x8 bf[4];
                    #pragma unroll
                    for (int v = 0; v < 4; ++v)
                        bf[v] = *(const bf16x8*)(znb + (size_t)(pkB[v] & 8191) * D + s * 32 + quad * 8);
                    #pragma unroll
                    for (int u = 0; u < 4; ++u)
                        #pragma unroll
                        for (int v = 0; v < 4; ++v)
                            ac[u][v] = __builtin_amdgcn_mfma_f32_16x16x32_bf16(afrag[u][s], bf[v], ac[u][v], 0, 0, 0);
                }

                // epilogue: C/D col=lane&15, row=quad*4+reg (m89/m91-verified)
                #pragma unroll
                for (int v = 0; v < 4; ++v) {
                    const unsigned pj = (unsigned)pkB[v];
                    #pragma unroll
                    for (int u = 0; u < 4; ++u)
                        #pragma unroll
                        for (int r = 0; r < 4; ++r) {
                            const int s16 = u * 4 + r;
                            unsigned key = (__float_as_uint(ac[u][v][r] + 2.0f) & 0xFFFFE000u) | (pj & 8191u);
                            bool sel = (((unsigned)cpk[s16] ^ pj) & 0xFFFFE000u) != 0u;
                            if (isPos) best[s16] = umn(best[s16], sel ? key : 0xFFFFFFFFu);
                            else       best[s16] = umx(best[s16], sel ? key : 0u);
                        }
                }
            }

            #pragma unroll
            for (int mm = 1; mm < 16; mm <<= 1)
                #pragma unroll
                for (int s = 0; s < 16; ++s) {
                    unsigned o = (unsigned)__shfl_xor((int)best[s], mm, 64);
                    best[s] = isPos ? umn(best[s], o) : umx(best[s], o);
                }
            if (m == 0) {
                unsigned* dstk = isPos ? posk : negk;
                #pragma unroll
                for (int s = 0; s < 16; ++s)
                    dstk[cpk[s] & 8191] = best[s];   // dup slots rewrite identical values
            }
        }
    }

    grid.sync();

    // ---------------- phase C: hinge + reduce (32 rows/block) ----------------
    {
        const int rb = t >> 4;          // 16 row-slots
        const int l  = t & 15;
        float lsum = 0.f, vsum = 0.f;
        #pragma unroll
        for (int p = 0; p < 2; ++p) {
            const int row = b * 32 + p * 16 + rb;
            unsigned mp = posk[row], mn = negk[row];
            bool valid = (mp != 0xFFFFFFFFu) && (mn != 0u);
            int pi = valid ? (int)(mp & 8191u) : 0;
            int ni = valid ? (int)(mn & 8191u) : 0;
            float ia = invn[row], ip = invn[pi], iq = invn[ni];
            const float4* za = (const float4*)(z + (size_t)row * D);
            const float4* zp = (const float4*)(z + (size_t)pi * D);
            const float4* zq = (const float4*)(z + (size_t)ni * D);
            float sap = 0.f, san = 0.f;
            #pragma unroll
            for (int k = 0; k < 2; ++k) {
                float4 a = za[l * 2 + k], pp = zp[l * 2 + k], qq = zq[l * 2 + k];
                float d;
                d = a.x * ia - pp.x * ip + PD_EPS; sap += d * d;
                d = a.y * ia - pp.y * ip + PD_EPS; sap += d * d;
                d = a.z * ia - pp.z * ip + PD_EPS; sap += d * d;
                d = a.w * ia - pp.w * ip + PD_EPS; sap += d * d;
                d = a.x * ia - qq.x * iq + PD_EPS; san += d * d;
                d = a.y * ia - qq.y * iq + PD_EPS; san += d * d;
                d = a.z * ia - qq.z * iq + PD_EPS; san += d * d;
                d = a.w * ia - qq.w * iq + PD_EPS; san += d * d;
            }
            #pragma unroll
            for (int mm = 1; mm < 16; mm <<= 1) {
                sap += __shfl_xor(sap, mm, 64);
                san += __shfl_xor(san, mm, 64);
            }
            if (l == 0) {
                float lo = fmaxf(sqrtf(sap) - sqrtf(san) + MARGIN, 0.0f);
                lsum += valid ? lo : 0.0f;
                vsum += valid ? 1.0f : 0.0f;
            }
        }
        __syncthreads();   // ls/vs reuse barrier (after phase A/B LDS use)
        if (l == 0) { ls[rb] = lsum; vs[rb] = vsum; }
        __syncthreads();
        if (t == 0) {
            float s = 0.f, c = 0.f;
            #pragma unroll
            for (int i = 0; i < 16; ++i) { s += ls[i]; c += vs[i]; }
            atomicAdd(&acc[0], s);
            atomicAdd(&acc[1], c);
            __threadfence();
            unsigned old = atomicAdd((unsigned*)&acc[2], 1u);
            if (old == (unsigned)(gridDim.x - 1)) {
                float S = atomicAdd(&acc[0], 0.0f);
                float C = atomicAdd(&acc[1], 0.0f);
                out[0] = (C > 0.f) ? S / fmaxf(C, 1.f) : 0.f;
            }
        }
    }
}

extern "C" void kernel_launch(void* const* d_in, const int* in_sizes, int n_in,
                              void* d_out, int out_size, void* d_ws, size_t ws_size,
                              hipStream_t stream) {
    const float* z        = (const float*)d_in[0];
    const int*   labels   = (const int*)d_in[1];
    const int*   subjects = (const int*)d_in[2];
    float* out = (float*)d_out;

    char* ws = (char*)d_ws;
    unsigned short* znb  = (unsigned short*)(ws);               // 2 MB
    float*    invn     = (float*)   (ws + 2097152);             // 32 KB
    int*      clsIdx   = (int*)     (ws + 2129920);             // 64 KB
    int*      subIdx   = (int*)     (ws + 2195456);             // 64 KB
    unsigned* posk     = (unsigned*)(ws + 2260992);             // 32 KB
    unsigned* negk     = (unsigned*)(ws + 2293760);             // 32 KB
    int*      counters = (int*)     (ws + 2326528);             // 48 ints
    float*    acc      = (float*)   (ws + 2326528 + 48 * 4);    // 3 floats

    void* args[] = {(void*)&z, (void*)&labels, (void*)&subjects, (void*)&znb,
                    (void*)&invn, (void*)&counters, (void*)&clsIdx, (void*)&subIdx,
                    (void*)&posk, (void*)&negk, (void*)&acc, (void*)&out};
    hipLaunchCooperativeKernel((const void*)k_fused, dim3(256), dim3(256), args, 0, stream);
}

// Round 7
// 118.634 us; speedup vs baseline: 1.4995x; 1.4995x over previous
//
#include <hip/hip_runtime.h>
#include <math.h>

#define N 8192
#define D 128
#define MARGIN 0.2f
#define PD_EPS 1e-6f
#define CLS_STRIDE 1024   // max rows per class bucket (16 classes, avg 512)
#define SUB_STRIDE 512    // max rows per subject bucket (32 subjects, avg 256)

typedef __attribute__((ext_vector_type(8))) short bf16x8;  // 8 bf16 = 4 VGPRs
typedef __attribute__((ext_vector_type(4))) float f32x4;

__device__ __forceinline__ unsigned short f2bf(float f) {
    unsigned u = __float_as_uint(f);
    u += 0x7FFFu + ((u >> 16) & 1u);   // round-to-nearest-even
    return (unsigned short)(u >> 16);
}
__device__ __forceinline__ unsigned umn(unsigned a, unsigned b) { return a < b ? a : b; }
__device__ __forceinline__ unsigned umx(unsigned a, unsigned b) { return a > b ? a : b; }

// ------- kernel 1: role-split prep ------------------------------------------
// blocks 0..47: bucket owners (0..15 class, 16..47 subject). Labels/subjects
// preloaded into 64 VGPRs (validated in round 6), then 32 in-register ballot
// compaction steps. Deterministic (row order preserved).
// blocks 48..2095: normalize 4 rows each -> bf16 rows + invnorm.
__global__ __launch_bounds__(256) void k_prep(const float* __restrict__ z,
                                              const int* __restrict__ labels,
                                              const int* __restrict__ subjects,
                                              unsigned short* __restrict__ znb,
                                              float* __restrict__ invn,
                                              int* __restrict__ counters,
                                              int* __restrict__ clsIdx,
                                              int* __restrict__ subIdx,
                                              float* __restrict__ acc) {
    const int b = blockIdx.x;
    const int t = threadIdx.x;
    const int wave = t >> 6, lane = t & 63;
    if (b < 48) {
        const bool isCls = b < 16;
        const int  tgt   = isCls ? b : b - 16;
        __shared__ int wcnt[4];
        __shared__ int blkbase;
        // preload the whole label/subject stream into registers
        int keyv[32], otherv[32];
        #pragma unroll
        for (int r = 0; r < 32; ++r) {
            int row = r * 256 + t;
            int lab = labels[row], sub = subjects[row];
            keyv[r]   = isCls ? lab : sub;
            otherv[r] = isCls ? sub : lab;
        }
        if (b == 0 && t < 3) acc[t] = 0.0f;   // loss-sum, valid-cnt, done-counter
        if (t == 0) blkbase = 0;
        __syncthreads();
        int* dst = isCls ? (clsIdx + tgt * CLS_STRIDE) : (subIdx + tgt * SUB_STRIDE);
        const int stride = isCls ? CLS_STRIDE : SUB_STRIDE;
        #pragma unroll
        for (int r = 0; r < 32; ++r) {
            bool pred = (keyv[r] == tgt);
            unsigned long long mask = __ballot(pred);
            int lrank = __popcll(mask & ((1ull << lane) - 1ull));
            if (lane == 0) wcnt[wave] = __popcll(mask);
            __syncthreads();
            int wb = 0;
            #pragma unroll
            for (int w = 0; w < 4; ++w) if (w < wave) wb += wcnt[w];
            int tot = wcnt[0] + wcnt[1] + wcnt[2] + wcnt[3];
            int pos = blkbase + wb + lrank;
            if (pred && pos < stride) dst[pos] = (otherv[r] << 13) | (r * 256 + t);
            __syncthreads();
            if (t == 0) blkbase += tot;
        }
        __syncthreads();
        if (t == 0) counters[isCls ? tgt : 16 + tgt] = blkbase;
    } else {
        int row = (b - 48) * 4 + wave;
        float2 v = ((const float2*)(z + (size_t)row * D))[lane];
        float ss = v.x * v.x + v.y * v.y;
        #pragma unroll
        for (int m = 1; m < 64; m <<= 1) ss += __shfl_xor(ss, m, 64);
        float norm = fmaxf(sqrtf(ss), 1e-12f);
        ushort2 bb; bb.x = f2bf(v.x / norm); bb.y = f2bf(v.y / norm);
        ((ushort2*)(znb + (size_t)row * D))[lane] = bb;
        if (lane == 0) invn[row] = 1.0f / norm;
    }
}

// ------- kernel 2: bucketed MFMA mining (unchanged, absmax-0 verified) -------
// blocks 0..255: pos (class c=b>>4, atile=b&15); 256..511: neg (subj=t>>3, atile=t&7).
// One wave per block, 64 anchors, sweeps all 64-j tiles of its bucket.
__global__ __launch_bounds__(64, 2) void k_mine(const unsigned short* __restrict__ znb,
                                                const int* __restrict__ counters,
                                                const int* __restrict__ clsIdx,
                                                const int* __restrict__ subIdx,
                                                unsigned* __restrict__ posk,
                                                unsigned* __restrict__ negk) {
    const int b = blockIdx.x;
    const bool isPos = b < 256;
    const int* idx; int cnt, atile;
    if (isPos) {
        int c = b >> 4; atile = b & 15;
        idx = clsIdx + c * CLS_STRIDE;
        cnt = min(counters[c], CLS_STRIDE);
    } else {
        int t = b - 256; int su = t >> 3; atile = t & 7;
        idx = subIdx + su * SUB_STRIDE;
        cnt = min(counters[16 + su], SUB_STRIDE);
    }
    if (atile * 64 >= cnt) return;

    const int lane = threadIdx.x;
    const int m = lane & 15, quad = lane >> 4;

    // A fragments (A[m=lane&15][k=quad*8+j], m89-verified)
    bf16x8 afrag[4][4];
    #pragma unroll
    for (int u = 0; u < 4; ++u) {
        int sl = min(atile * 64 + u * 16 + m, cnt - 1);
        size_t row = (size_t)(idx[sl] & 8191);
        #pragma unroll
        for (int s = 0; s < 4; ++s)
            afrag[u][s] = *(const bf16x8*)(znb + row * D + s * 32 + quad * 8);
    }
    int cpk[16];
    #pragma unroll
    for (int u = 0; u < 4; ++u)
        #pragma unroll
        for (int r = 0; r < 4; ++r)
            cpk[u * 4 + r] = idx[min(atile * 64 + u * 16 + quad * 4 + r, cnt - 1)];

    unsigned best[16];
    #pragma unroll
    for (int s = 0; s < 16; ++s) best[s] = isPos ? 0xFFFFFFFFu : 0u;

    const int njt = (cnt + 63) >> 6;
    for (int t = 0; t < njt; ++t) {
        int pkB[4];
        #pragma unroll
        for (int v = 0; v < 4; ++v)
            pkB[v] = idx[min(t * 64 + v * 16 + m, cnt - 1)];

        f32x4 acc[4][4];
        #pragma unroll
        for (int u = 0; u < 4; ++u)
            #pragma unroll
            for (int v = 0; v < 4; ++v)
                acc[u][v] = (f32x4){0.f, 0.f, 0.f, 0.f};

        #pragma unroll
        for (int s = 0; s < 4; ++s) {
            bf16x8 bf[4];
            #pragma unroll
            for (int v = 0; v < 4; ++v)
                bf[v] = *(const bf16x8*)(znb + (size_t)(pkB[v] & 8191) * D + s * 32 + quad * 8);
            #pragma unroll
            for (int u = 0; u < 4; ++u)
                #pragma unroll
                for (int v = 0; v < 4; ++v)
                    acc[u][v] = __builtin_amdgcn_mfma_f32_16x16x32_bf16(afrag[u][s], bf[v], acc[u][v], 0, 0, 0);
        }

        // epilogue: C/D col=lane&15, row=quad*4+reg (m89/m91-verified)
        #pragma unroll
        for (int v = 0; v < 4; ++v) {
            const unsigned pj = (unsigned)pkB[v];
            #pragma unroll
            for (int u = 0; u < 4; ++u)
                #pragma unroll
                for (int r = 0; r < 4; ++r) {
                    const int s16 = u * 4 + r;
                    unsigned key = (__float_as_uint(acc[u][v][r] + 2.0f) & 0xFFFFE000u) | (pj & 8191u);
                    bool sel = (((unsigned)cpk[s16] ^ pj) & 0xFFFFE000u) != 0u;  // field differs
                    if (isPos) best[s16] = umn(best[s16], sel ? key : 0xFFFFFFFFu);
                    else       best[s16] = umx(best[s16], sel ? key : 0u);
                }
        }
    }

    #pragma unroll
    for (int mm = 1; mm < 16; mm <<= 1)
        #pragma unroll
        for (int s = 0; s < 16; ++s) {
            unsigned o = (unsigned)__shfl_xor((int)best[s], mm, 64);
            best[s] = isPos ? umn(best[s], o) : umx(best[s], o);
        }
    if (m == 0) {
        unsigned* dst = isPos ? posk : negk;
        #pragma unroll
        for (int s = 0; s < 16; ++s)
            dst[cpk[s] & 8191] = best[s];   // dup slots rewrite identical values
    }
}

// ------- kernel 3: fp32 hinge + fused reduce (unchanged, absmax-0 verified) --
__global__ __launch_bounds__(256) void k_final(const float* __restrict__ z,
                                               const float* __restrict__ invn,
                                               const unsigned* __restrict__ posk,
                                               const unsigned* __restrict__ negk,
                                               float* __restrict__ acc,
                                               float* __restrict__ out) {
    const int rb = threadIdx.x >> 4;          // 16 rows per block
    const int l  = threadIdx.x & 15;
    const int row = blockIdx.x * 16 + rb;
    unsigned mp = posk[row], mn = negk[row];
    bool valid = (mp != 0xFFFFFFFFu) && (mn != 0u);
    int pi = valid ? (int)(mp & 8191u) : 0;
    int ni = valid ? (int)(mn & 8191u) : 0;
    float ia = invn[row], ip = invn[pi], iq = invn[ni];
    const float4* za = (const float4*)(z + (size_t)row * D);
    const float4* zp = (const float4*)(z + (size_t)pi * D);
    const float4* zq = (const float4*)(z + (size_t)ni * D);
    float sap = 0.f, san = 0.f;
    #pragma unroll
    for (int k = 0; k < 2; ++k) {
        float4 a = za[l * 2 + k], p = zp[l * 2 + k], q = zq[l * 2 + k];
        float d;
        d = a.x * ia - p.x * ip + PD_EPS; sap += d * d;
        d = a.y * ia - p.y * ip + PD_EPS; sap += d * d;
        d = a.z * ia - p.z * ip + PD_EPS; sap += d * d;
        d = a.w * ia - p.w * ip + PD_EPS; sap += d * d;
        d = a.x * ia - q.x * iq + PD_EPS; san += d * d;
        d = a.y * ia - q.y * iq + PD_EPS; san += d * d;
        d = a.z * ia - q.z * iq + PD_EPS; san += d * d;
        d = a.w * ia - q.w * iq + PD_EPS; san += d * d;
    }
    #pragma unroll
    for (int mm = 1; mm < 16; mm <<= 1) {
        sap += __shfl_xor(sap, mm, 64);
        san += __shfl_xor(san, mm, 64);
    }
    __shared__ float ls[16], vs[16];
    if (l == 0) {
        float lo = fmaxf(sqrtf(sap) - sqrtf(san) + MARGIN, 0.0f);
        ls[rb] = valid ? lo : 0.0f;
        vs[rb] = valid ? 1.0f : 0.0f;
    }
    __syncthreads();
    if (threadIdx.x == 0) {
        float s = 0.f, c = 0.f;
        #pragma unroll
        for (int i = 0; i < 16; ++i) { s += ls[i]; c += vs[i]; }
        atomicAdd(&acc[0], s);
        atomicAdd(&acc[1], c);
        __threadfence();
        unsigned old = atomicAdd((unsigned*)&acc[2], 1u);
        if (old == (unsigned)(gridDim.x - 1)) {
            float S = atomicAdd(&acc[0], 0.0f);
            float C = atomicAdd(&acc[1], 0.0f);
            out[0] = (C > 0.f) ? S / fmaxf(C, 1.f) : 0.f;
        }
    }
}

extern "C" void kernel_launch(void* const* d_in, const int* in_sizes, int n_in,
                              void* d_out, int out_size, void* d_ws, size_t ws_size,
                              hipStream_t stream) {
    const float* z        = (const float*)d_in[0];
    const int*   labels   = (const int*)d_in[1];
    const int*   subjects = (const int*)d_in[2];
    float* out = (float*)d_out;

    char* ws = (char*)d_ws;
    unsigned short* znb  = (unsigned short*)(ws);               // 2 MB
    float*    invn     = (float*)   (ws + 2097152);             // 32 KB
    int*      clsIdx   = (int*)     (ws + 2129920);             // 64 KB
    int*      subIdx   = (int*)     (ws + 2195456);             // 64 KB
    unsigned* posk     = (unsigned*)(ws + 2260992);             // 32 KB
    unsigned* negk     = (unsigned*)(ws + 2293760);             // 32 KB
    int*      counters = (int*)     (ws + 2326528);             // 48 ints
    float*    acc      = (float*)   (ws + 2326528 + 48 * 4);    // 3 floats

    k_prep<<<dim3(48 + N / 4), dim3(256), 0, stream>>>(z, labels, subjects, znb, invn,
                                                       counters, clsIdx, subIdx, acc);
    k_mine<<<dim3(512), dim3(64), 0, stream>>>(znb, counters, clsIdx, subIdx, posk, negk);
    k_final<<<dim3(N / 16), dim3(256), 0, stream>>>(z, invn, posk, negk, acc, out);
}